// Round 1
// baseline (4704.202 us; speedup 1.0000x reference)
//
#include <hip/hip_runtime.h>
#include <math.h>

#define NN 4096
#define TSTEPS 50

// ws float offsets
#define RS0 (0*NN)
#define RS1 (1*NN)
#define RS2 (2*NN)
#define RI0 (3*NN)
#define RI1 (4*NN)
#define VI0 (5*NN)
#define VA0 (6*NN)
#define VB1 (7*NN)
#define VI1 (8*NN)
#define VA1 (9*NN)
#define VB2 (10*NN)
#define VB0 (11*NN)
#define RD  (12*NN)
#define SS0 (13*NN)
#define SS1 (14*NN)
#define SS2 (15*NN)
#define II0 (16*NN)
#define II1 (17*NN)
#define MEANS (18*NN)

__device__ __forceinline__ float softplusf(float x){
    // stable log(1+exp(x))
    return fmaxf(x, 0.0f) + log1pf(expf(-fabsf(x)));
}

__global__ void k_init(const float* __restrict__ data,
                       const float* __restrict__ s0, const float* __restrict__ s1,
                       const float* __restrict__ s2, const float* __restrict__ i0,
                       const float* __restrict__ i1, float* __restrict__ ws){
    int i = blockIdx.x*blockDim.x + threadIdx.x;
    if (i >= NN) return;
    ws[RD+i] = softplusf(data[i]);
    float a=s0[i], b=s1[i], c=s2[i], d=i0[i], e=i1[i];
    ws[SS0+i]=a; ws[SS1+i]=b; ws[SS2+i]=c; ws[II0+i]=d; ws[II1+i]=e;
    ws[RS0+i]=softplusf(a); ws[RS1+i]=softplusf(b); ws[RS2+i]=softplusf(c);
    ws[RI0+i]=softplusf(d); ws[RI1+i]=softplusf(e);
}

// one full 64-lane wave computes dot(w[0..N), x[0..N)); result valid on lane 0
__device__ __forceinline__ float wave_dot(const float* __restrict__ w,
                                          const float* __restrict__ x){
    int lane = threadIdx.x & 63;
    float acc = 0.0f;
#pragma unroll
    for (int k = 0; k < 16; ++k){
        float4 wv = *reinterpret_cast<const float4*>(w + k*256 + lane*4);
        float4 xv = *reinterpret_cast<const float4*>(x + k*256 + lane*4);
        acc = fmaf(wv.x, xv.x, acc);
        acc = fmaf(wv.y, xv.y, acc);
        acc = fmaf(wv.z, xv.z, acc);
        acc = fmaf(wv.w, xv.w, acc);
    }
#pragma unroll
    for (int off = 32; off > 0; off >>= 1) acc += __shfl_down(acc, off, 64);
    return acc;
}

// loop-invariant: vb0[row] = dot(wpf0[row,:], rho(data))
__global__ void k_vb0(const float* __restrict__ wpf0, float* __restrict__ ws){
    int wid = (blockIdx.x*blockDim.x + threadIdx.x) >> 6;
    int row = wid & (NN-1);
    float r = wave_dot(wpf0 + (size_t)row*NN, ws + RD);
    if ((threadIdx.x & 63) == 0) ws[VB0+row] = r;
}

__global__ void k_means(float* __restrict__ ws){
    int tid = threadIdx.x; // 1024 threads
    float a = 0.f, b = 0.f;
    for (int i = tid; i < NN; i += 1024){ a += ws[RS1+i]; b += ws[RS2+i]; }
#pragma unroll
    for (int off = 32; off > 0; off >>= 1){
        a += __shfl_down(a, off, 64);
        b += __shfl_down(b, off, 64);
    }
    __shared__ float sa[16], sb[16];
    int wv = tid >> 6, lane = tid & 63;
    if (lane == 0){ sa[wv] = a; sb[wv] = b; }
    __syncthreads();
    if (tid == 0){
        float ta = 0.f, tb = 0.f;
        for (int k = 0; k < 16; ++k){ ta += sa[k]; tb += sb[k]; }
        ws[MEANS+0] = ta / (float)NN;
        ws[MEANS+1] = tb / (float)NN;
    }
}

// 6 jobs x 4096 rows, one wave per (job,row); jobs 1 and 4 do two dots
__global__ void k_matvec(const float* __restrict__ wpf1, const float* __restrict__ wpf2,
                         const float* __restrict__ wpb0, const float* __restrict__ wpb1,
                         const float* __restrict__ wip0, const float* __restrict__ wip1,
                         const float* __restrict__ wpi0, const float* __restrict__ wpi1,
                         float* __restrict__ ws){
    int wid = (blockIdx.x*blockDim.x + threadIdx.x) >> 6;
    int job = wid >> 12;          // / 4096
    int row = wid & (NN-1);
    size_t ro = (size_t)row * NN;
    float r; float* out;
    switch (job){
      case 0: r = wave_dot(wip0+ro, ws+RS0);                              out = ws+VI0; break;
      case 1: r = wave_dot(wpi0+ro, ws+RI0) + wave_dot(wpb0+ro, ws+RS1);  out = ws+VA0; break;
      case 2: r = wave_dot(wpf1+ro, ws+RS0);                              out = ws+VB1; break;
      case 3: r = wave_dot(wip1+ro, ws+RS1);                              out = ws+VI1; break;
      case 4: r = wave_dot(wpi1+ro, ws+RI1) + wave_dot(wpb1+ro, ws+RS2);  out = ws+VA1; break;
      default: r = wave_dot(wpf2+ro, ws+RS1);                             out = ws+VB2; break;
    }
    if ((threadIdx.x & 63) == 0) out[row] = r;
}

__global__ void k_update(float* __restrict__ ws){
    const float DT=0.1f, GA=0.8f, GB=1.0f, GD=1.0f, GLK=0.1f, GSOM=0.8f;
    int i = blockIdx.x*blockDim.x + threadIdx.x;
    if (i >= NN) return;
    float s0=ws[SS0+i], s1=ws[SS1+i], s2=ws[SS2+i], i0=ws[II0+i], i1=ws[II1+i];
    float vb0=ws[VB0+i], va0=ws[VA0+i], vb1=ws[VB1+i], va1=ws[VA1+i], vb2=ws[VB2+i];
    float vi0=ws[VI0+i], vi1=ws[VI1+i];
    float m0=ws[MEANS+0], m1=ws[MEANS+1];
    float ds0 = -GLK*s0 + GB*(vb0-s0) + GA*(va0-s0);
    float ds1 = -GLK*s1 + GB*(vb1-s1) + GA*(va1-s1);
    float ds2 = -GLK*s2 + GB*(vb2-s2);
    float di0 = -GLK*i0 + GD*(vi0-i0) + GSOM*(m0-i0);
    float di1 = -GLK*i1 + GD*(vi1-i1) + GSOM*(m1-i1);
    float ns0 = s0 + DT*ds0;
    float ns1 = s1 + DT*ds1;
    float ns2 = DT*ds2;          // faithful to reference: assignment, not +=
    float ni0 = i0 + DT*di0;
    float ni1 = i1 + DT*di1;
    ws[SS0+i]=ns0; ws[SS1+i]=ns1; ws[SS2+i]=ns2; ws[II0+i]=ni0; ws[II1+i]=ni1;
    ws[RS0+i]=softplusf(ns0); ws[RS1+i]=softplusf(ns1); ws[RS2+i]=softplusf(ns2);
    ws[RI0+i]=softplusf(ni0); ws[RI1+i]=softplusf(ni1);
}

__global__ void k_out(const float* __restrict__ ws, float* __restrict__ out){
    int i = blockIdx.x*blockDim.x + threadIdx.x;
    if (i >= 5*NN) return;
    int which = i >> 12;   // /NN
    int off = i & (NN-1);
    const int src[5] = {SS0, SS1, SS2, II0, II1};
    out[i] = ws[src[which] + off];
}

extern "C" void kernel_launch(void* const* d_in, const int* in_sizes, int n_in,
                              void* d_out, int out_size, void* d_ws, size_t ws_size,
                              hipStream_t stream) {
    const float* data = (const float*)d_in[0];
    const float* s0   = (const float*)d_in[1];
    const float* s1   = (const float*)d_in[2];
    const float* s2   = (const float*)d_in[3];
    const float* i0   = (const float*)d_in[4];
    const float* i1   = (const float*)d_in[5];
    const float* wpf0 = (const float*)d_in[6];
    const float* wpf1 = (const float*)d_in[7];
    const float* wpf2 = (const float*)d_in[8];
    const float* wpb0 = (const float*)d_in[9];
    const float* wpb1 = (const float*)d_in[10];
    const float* wip0 = (const float*)d_in[11];
    const float* wip1 = (const float*)d_in[12];
    const float* wpi0 = (const float*)d_in[13];
    const float* wpi1 = (const float*)d_in[14];
    float* ws  = (float*)d_ws;
    float* out = (float*)d_out;

    k_init<<<(NN+255)/256, 256, 0, stream>>>(data, s0, s1, s2, i0, i1, ws);
    k_vb0<<<NN/4, 256, 0, stream>>>(wpf0, ws);   // 4096 waves, 4/block

    for (int t = 0; t < TSTEPS; ++t){
        k_means<<<1, 1024, 0, stream>>>(ws);
        k_matvec<<<6*NN/4, 256, 0, stream>>>(wpf1, wpf2, wpb0, wpb1,
                                             wip0, wip1, wpi0, wpi1, ws);
        k_update<<<(NN+255)/256, 256, 0, stream>>>(ws);
    }
    k_out<<<(5*NN+255)/256, 256, 0, stream>>>(ws, out);
}

// Round 2
// 4636.812 us; speedup vs baseline: 1.0145x; 1.0145x over previous
//
#include <hip/hip_runtime.h>
#include <math.h>

#define NN 4096
#define TSTEPS 50

// ws float offsets
enum {
  RS0 = 0*NN, RS1 = 1*NN, RS2 = 2*NN, RI0 = 3*NN, RI1 = 4*NN,
  VI0 = 5*NN, VA0A = 6*NN, VA0B = 7*NN, VB1 = 8*NN, VI1 = 9*NN,
  VA1A = 10*NN, VA1B = 11*NN, VB2 = 12*NN, VB0 = 13*NN, RD = 14*NN,
  SS0 = 15*NN, SS1 = 16*NN, SS2 = 17*NN, II0 = 18*NN, II1 = 19*NN,
  MEANS = 20*NN
};

__device__ __forceinline__ float softplusf(float x){
    return fmaxf(x, 0.0f) + log1pf(expf(-fabsf(x)));
}

__global__ void k_init(const float* __restrict__ data,
                       const float* __restrict__ s0, const float* __restrict__ s1,
                       const float* __restrict__ s2, const float* __restrict__ i0,
                       const float* __restrict__ i1, float* __restrict__ ws){
    int i = blockIdx.x*blockDim.x + threadIdx.x;
    if (i >= NN) return;
    ws[RD+i] = softplusf(data[i]);
    float a=s0[i], b=s1[i], c=s2[i], d=i0[i], e=i1[i];
    ws[SS0+i]=a; ws[SS1+i]=b; ws[SS2+i]=c; ws[II0+i]=d; ws[II1+i]=e;
    ws[RS0+i]=softplusf(a); ws[RS1+i]=softplusf(b); ws[RS2+i]=softplusf(c);
    ws[RI0+i]=softplusf(d); ws[RI1+i]=softplusf(e);
}

// block = 256 threads (4 waves); each wave computes one full row-dot.
// w rows streamed with 8 batched float4 loads (in flight together), x from LDS.
__device__ __forceinline__ void mv_rows(const float* __restrict__ w,
                                        const float* __restrict__ xg,
                                        float* __restrict__ o,
                                        int rowbase, float* xs){
    for (int k = threadIdx.x; k < NN/4; k += 256)
        reinterpret_cast<float4*>(xs)[k] = reinterpret_cast<const float4*>(xg)[k];
    __syncthreads();
    int wv = threadIdx.x >> 6, lane = threadIdx.x & 63;
    int row = rowbase + wv;
    const float* wr = w + (size_t)row * NN;
    float acc = 0.f;
#pragma unroll
    for (int h = 0; h < 2; ++h){
        float4 wvv[8];
#pragma unroll
        for (int k = 0; k < 8; ++k)
            wvv[k] = *reinterpret_cast<const float4*>(wr + h*2048 + k*256 + lane*4);
#pragma unroll
        for (int k = 0; k < 8; ++k){
            float4 xv = *reinterpret_cast<const float4*>(xs + h*2048 + k*256 + lane*4);
            acc = fmaf(wvv[k].x, xv.x, acc);
            acc = fmaf(wvv[k].y, xv.y, acc);
            acc = fmaf(wvv[k].z, xv.z, acc);
            acc = fmaf(wvv[k].w, xv.w, acc);
        }
    }
#pragma unroll
    for (int off = 32; off; off >>= 1) acc += __shfl_down(acc, off, 64);
    if (lane == 0) o[row] = acc;
}

// loop-invariant vb0 = wpf0 @ rho(data)
__global__ __launch_bounds__(256) void k_vb0(const float* __restrict__ wpf0,
                                             float* __restrict__ ws){
    __shared__ float xs[NN];
    mv_rows(wpf0, ws + RD, ws + VB0, blockIdx.x * 4, xs);
}

// block 0: means of rs1, rs2.  blocks 1..8192: 8 jobs x 1024 blocks x 4 rows.
__global__ __launch_bounds__(256) void k_mv(const float* __restrict__ wip0,
                                            const float* __restrict__ wpi0,
                                            const float* __restrict__ wpb0,
                                            const float* __restrict__ wpf1,
                                            const float* __restrict__ wip1,
                                            const float* __restrict__ wpi1,
                                            const float* __restrict__ wpb1,
                                            const float* __restrict__ wpf2,
                                            float* __restrict__ ws){
    if (blockIdx.x == 0){
        int tid = threadIdx.x;
        float a = 0.f, c = 0.f;
        for (int i = tid; i < NN; i += 256){ a += ws[RS1+i]; c += ws[RS2+i]; }
#pragma unroll
        for (int off = 32; off; off >>= 1){
            a += __shfl_down(a, off, 64);
            c += __shfl_down(c, off, 64);
        }
        __shared__ float sa[4], sc[4];
        int wv = tid >> 6, lane = tid & 63;
        if (lane == 0){ sa[wv] = a; sc[wv] = c; }
        __syncthreads();
        if (tid == 0){
            ws[MEANS+0] = (sa[0]+sa[1]+sa[2]+sa[3]) * (1.f/NN);
            ws[MEANS+1] = (sc[0]+sc[1]+sc[2]+sc[3]) * (1.f/NN);
        }
        return;
    }
    int b = blockIdx.x - 1;
    int job = b >> 10;
    int rowbase = (b & 1023) * 4;
    const float* w; const float* x; float* o;
    switch (job){
      case 0: w = wip0; x = ws+RS0; o = ws+VI0;  break;
      case 1: w = wpi0; x = ws+RI0; o = ws+VA0A; break;
      case 2: w = wpb0; x = ws+RS1; o = ws+VA0B; break;
      case 3: w = wpf1; x = ws+RS0; o = ws+VB1;  break;
      case 4: w = wip1; x = ws+RS1; o = ws+VI1;  break;
      case 5: w = wpi1; x = ws+RI1; o = ws+VA1A; break;
      case 6: w = wpb1; x = ws+RS2; o = ws+VA1B; break;
      default:w = wpf2; x = ws+RS1; o = ws+VB2;  break;
    }
    __shared__ float xs[NN];
    mv_rows(w, x, o, rowbase, xs);
}

__global__ void k_update(float* __restrict__ ws){
    const float DT=0.1f, GA=0.8f, GB=1.0f, GD=1.0f, GLK=0.1f, GSOM=0.8f;
    int i = blockIdx.x*blockDim.x + threadIdx.x;
    if (i >= NN) return;
    float s0=ws[SS0+i], s1=ws[SS1+i], s2=ws[SS2+i], i0=ws[II0+i], i1=ws[II1+i];
    float vb0=ws[VB0+i], vb1=ws[VB1+i], vb2=ws[VB2+i];
    float va0=ws[VA0A+i]+ws[VA0B+i];
    float va1=ws[VA1A+i]+ws[VA1B+i];
    float vi0=ws[VI0+i], vi1=ws[VI1+i];
    float m0=ws[MEANS+0], m1=ws[MEANS+1];
    float ds0 = -GLK*s0 + GB*(vb0-s0) + GA*(va0-s0);
    float ds1 = -GLK*s1 + GB*(vb1-s1) + GA*(va1-s1);
    float ds2 = -GLK*s2 + GB*(vb2-s2);
    float di0 = -GLK*i0 + GD*(vi0-i0) + GSOM*(m0-i0);
    float di1 = -GLK*i1 + GD*(vi1-i1) + GSOM*(m1-i1);
    float ns0 = s0 + DT*ds0;
    float ns1 = s1 + DT*ds1;
    float ns2 = DT*ds2;          // faithful to reference: assignment, not +=
    float ni0 = i0 + DT*di0;
    float ni1 = i1 + DT*di1;
    ws[SS0+i]=ns0; ws[SS1+i]=ns1; ws[SS2+i]=ns2; ws[II0+i]=ni0; ws[II1+i]=ni1;
    ws[RS0+i]=softplusf(ns0); ws[RS1+i]=softplusf(ns1); ws[RS2+i]=softplusf(ns2);
    ws[RI0+i]=softplusf(ni0); ws[RI1+i]=softplusf(ni1);
}

__global__ void k_out(const float* __restrict__ ws, float* __restrict__ out){
    int i = blockIdx.x*blockDim.x + threadIdx.x;
    if (i >= 5*NN) return;
    int which = i >> 12;
    int off = i & (NN-1);
    const int src[5] = {SS0, SS1, SS2, II0, II1};
    out[i] = ws[src[which] + off];
}

extern "C" void kernel_launch(void* const* d_in, const int* in_sizes, int n_in,
                              void* d_out, int out_size, void* d_ws, size_t ws_size,
                              hipStream_t stream) {
    const float* data = (const float*)d_in[0];
    const float* s0   = (const float*)d_in[1];
    const float* s1   = (const float*)d_in[2];
    const float* s2   = (const float*)d_in[3];
    const float* i0   = (const float*)d_in[4];
    const float* i1   = (const float*)d_in[5];
    const float* wpf0 = (const float*)d_in[6];
    const float* wpf1 = (const float*)d_in[7];
    const float* wpf2 = (const float*)d_in[8];
    const float* wpb0 = (const float*)d_in[9];
    const float* wpb1 = (const float*)d_in[10];
    const float* wip0 = (const float*)d_in[11];
    const float* wip1 = (const float*)d_in[12];
    const float* wpi0 = (const float*)d_in[13];
    const float* wpi1 = (const float*)d_in[14];
    float* ws  = (float*)d_ws;
    float* out = (float*)d_out;

    k_init<<<(NN+255)/256, 256, 0, stream>>>(data, s0, s1, s2, i0, i1, ws);
    k_vb0<<<NN/4, 256, 0, stream>>>(wpf0, ws);

    for (int t = 0; t < TSTEPS; ++t){
        k_mv<<<8*NN/4 + 1, 256, 0, stream>>>(wip0, wpi0, wpb0, wpf1,
                                             wip1, wpi1, wpb1, wpf2, ws);
        k_update<<<(NN+255)/256, 256, 0, stream>>>(ws);
    }
    k_out<<<(5*NN+255)/256, 256, 0, stream>>>(ws, out);
}

// Round 3
// 2303.772 us; speedup vs baseline: 2.0420x; 2.0127x over previous
//
#include <hip/hip_runtime.h>
#include <math.h>

#define NN 4096
#define TSTEPS 50

typedef _Float16 half8 __attribute__((ext_vector_type(8)));

// ws float offsets (state/vector arrays at front of ws)
enum {
  RS0 = 0*NN, RS1 = 1*NN, RS2 = 2*NN, RI0 = 3*NN, RI1 = 4*NN,
  VI0 = 5*NN, VA0A = 6*NN, VA0B = 7*NN, VB1 = 8*NN, VI1 = 9*NN,
  VA1A = 10*NN, VA1B = 11*NN, VB2 = 12*NN, VB0 = 13*NN, RD = 14*NN,
  SS0 = 15*NN, SS1 = 16*NN, SS2 = 17*NN, II0 = 18*NN, II1 = 19*NN,
  MEANS = 20*NN
};
#define WS_F32_FLOATS (21*NN)
#define WS_F32_BYTES  ((size_t)WS_F32_FLOATS*4)   // 344064, 256B-aligned
#define MAT_ELEMS     ((size_t)NN*NN)
#define WS_NEEDED_FP16 (WS_F32_BYTES + 8*MAT_ELEMS*2)

__device__ __forceinline__ float softplusf(float x){
    return fmaxf(x, 0.0f) + log1pf(expf(-fabsf(x)));
}

__global__ void k_init(const float* __restrict__ data,
                       const float* __restrict__ s0, const float* __restrict__ s1,
                       const float* __restrict__ s2, const float* __restrict__ i0,
                       const float* __restrict__ i1, float* __restrict__ ws){
    int i = blockIdx.x*blockDim.x + threadIdx.x;
    if (i >= NN) return;
    ws[RD+i] = softplusf(data[i]);
    float a=s0[i], b=s1[i], c=s2[i], d=i0[i], e=i1[i];
    ws[SS0+i]=a; ws[SS1+i]=b; ws[SS2+i]=c; ws[II0+i]=d; ws[II1+i]=e;
    ws[RS0+i]=softplusf(a); ws[RS1+i]=softplusf(b); ws[RS2+i]=softplusf(c);
    ws[RI0+i]=softplusf(d); ws[RI1+i]=softplusf(e);
}

// one-time fp32 -> fp16 weight conversion (8 elems/thread, coalesced)
__global__ __launch_bounds__(256) void k_cvt(const float* __restrict__ w,
                                             _Float16* __restrict__ o){
    size_t i = ((size_t)blockIdx.x*256 + threadIdx.x)*8;
    float4 a = *reinterpret_cast<const float4*>(w + i);
    float4 b = *reinterpret_cast<const float4*>(w + i + 4);
    half8 h;
    h[0]=(_Float16)a.x; h[1]=(_Float16)a.y; h[2]=(_Float16)a.z; h[3]=(_Float16)a.w;
    h[4]=(_Float16)b.x; h[5]=(_Float16)b.y; h[6]=(_Float16)b.z; h[7]=(_Float16)b.w;
    *reinterpret_cast<half8*>(o + i) = h;
}

// ---------- fp32 path (fallback + k_vb0) ----------
__device__ __forceinline__ void mv_rows(const float* __restrict__ w,
                                        const float* __restrict__ xg,
                                        float* __restrict__ o,
                                        int rowbase, float* xs){
    for (int k = threadIdx.x; k < NN/4; k += 256)
        reinterpret_cast<float4*>(xs)[k] = reinterpret_cast<const float4*>(xg)[k];
    __syncthreads();
    int wv = threadIdx.x >> 6, lane = threadIdx.x & 63;
    int row = rowbase + wv;
    const float* wr = w + (size_t)row * NN;
    float acc = 0.f;
#pragma unroll
    for (int h = 0; h < 2; ++h){
        float4 wvv[8];
#pragma unroll
        for (int k = 0; k < 8; ++k)
            wvv[k] = *reinterpret_cast<const float4*>(wr + h*2048 + k*256 + lane*4);
#pragma unroll
        for (int k = 0; k < 8; ++k){
            float4 xv = *reinterpret_cast<const float4*>(xs + h*2048 + k*256 + lane*4);
            acc = fmaf(wvv[k].x, xv.x, acc);
            acc = fmaf(wvv[k].y, xv.y, acc);
            acc = fmaf(wvv[k].z, xv.z, acc);
            acc = fmaf(wvv[k].w, xv.w, acc);
        }
    }
#pragma unroll
    for (int off = 32; off; off >>= 1) acc += __shfl_down(acc, off, 64);
    if (lane == 0) o[row] = acc;
}

__global__ __launch_bounds__(256) void k_vb0(const float* __restrict__ wpf0,
                                             float* __restrict__ ws){
    __shared__ float xs[NN];
    mv_rows(wpf0, ws + RD, ws + VB0, blockIdx.x * 4, xs);
}

__global__ __launch_bounds__(256) void k_mv(const float* __restrict__ wip0,
                                            const float* __restrict__ wpi0,
                                            const float* __restrict__ wpb0,
                                            const float* __restrict__ wpf1,
                                            const float* __restrict__ wip1,
                                            const float* __restrict__ wpi1,
                                            const float* __restrict__ wpb1,
                                            const float* __restrict__ wpf2,
                                            float* __restrict__ ws){
    if (blockIdx.x == 0){
        int tid = threadIdx.x;
        float a = 0.f, c = 0.f;
        for (int i = tid; i < NN; i += 256){ a += ws[RS1+i]; c += ws[RS2+i]; }
#pragma unroll
        for (int off = 32; off; off >>= 1){
            a += __shfl_down(a, off, 64);
            c += __shfl_down(c, off, 64);
        }
        __shared__ float sa[4], sc[4];
        int wv = tid >> 6, lane = tid & 63;
        if (lane == 0){ sa[wv] = a; sc[wv] = c; }
        __syncthreads();
        if (tid == 0){
            ws[MEANS+0] = (sa[0]+sa[1]+sa[2]+sa[3]) * (1.f/NN);
            ws[MEANS+1] = (sc[0]+sc[1]+sc[2]+sc[3]) * (1.f/NN);
        }
        return;
    }
    int b = blockIdx.x - 1;
    int job = b >> 10;
    int rowbase = (b & 1023) * 4;
    const float* w; const float* x; float* o;
    switch (job){
      case 0: w = wip0; x = ws+RS0; o = ws+VI0;  break;
      case 1: w = wpi0; x = ws+RI0; o = ws+VA0A; break;
      case 2: w = wpb0; x = ws+RS1; o = ws+VA0B; break;
      case 3: w = wpf1; x = ws+RS0; o = ws+VB1;  break;
      case 4: w = wip1; x = ws+RS1; o = ws+VI1;  break;
      case 5: w = wpi1; x = ws+RI1; o = ws+VA1A; break;
      case 6: w = wpb1; x = ws+RS2; o = ws+VA1B; break;
      default:w = wpf2; x = ws+RS1; o = ws+VB2;  break;
    }
    __shared__ float xs[NN];
    mv_rows(w, x, o, rowbase, xs);
}

// ---------- fp16-weight path ----------
// wave computes one full row: 8 batched 16B loads cover all 4096 halfs.
__device__ __forceinline__ void mv_rows_h(const _Float16* __restrict__ w,
                                          const float* __restrict__ xg,
                                          float* __restrict__ o,
                                          int rowbase, float* xs){
    for (int k = threadIdx.x; k < NN/4; k += 256)
        reinterpret_cast<float4*>(xs)[k] = reinterpret_cast<const float4*>(xg)[k];
    __syncthreads();
    int wv = threadIdx.x >> 6, lane = threadIdx.x & 63;
    int row = rowbase + wv;
    const half8* wr = reinterpret_cast<const half8*>(w + (size_t)row * NN);
    half8 wv8[8];
#pragma unroll
    for (int k = 0; k < 8; ++k) wv8[k] = wr[k*64 + lane];
    float acc = 0.f;
#pragma unroll
    for (int k = 0; k < 8; ++k){
        const float* xp = xs + k*512 + lane*8;
        float4 xa = *reinterpret_cast<const float4*>(xp);
        float4 xb = *reinterpret_cast<const float4*>(xp + 4);
        acc = fmaf((float)wv8[k][0], xa.x, acc);
        acc = fmaf((float)wv8[k][1], xa.y, acc);
        acc = fmaf((float)wv8[k][2], xa.z, acc);
        acc = fmaf((float)wv8[k][3], xa.w, acc);
        acc = fmaf((float)wv8[k][4], xb.x, acc);
        acc = fmaf((float)wv8[k][5], xb.y, acc);
        acc = fmaf((float)wv8[k][6], xb.z, acc);
        acc = fmaf((float)wv8[k][7], xb.w, acc);
    }
#pragma unroll
    for (int off = 32; off; off >>= 1) acc += __shfl_down(acc, off, 64);
    if (lane == 0) o[row] = acc;
}

__global__ __launch_bounds__(256) void k_mv_h(float* __restrict__ ws,
                                              const _Float16* __restrict__ wh){
    if (blockIdx.x == 0){
        int tid = threadIdx.x;
        float a = 0.f, c = 0.f;
        for (int i = tid; i < NN; i += 256){ a += ws[RS1+i]; c += ws[RS2+i]; }
#pragma unroll
        for (int off = 32; off; off >>= 1){
            a += __shfl_down(a, off, 64);
            c += __shfl_down(c, off, 64);
        }
        __shared__ float sa[4], sc[4];
        int wv = tid >> 6, lane = tid & 63;
        if (lane == 0){ sa[wv] = a; sc[wv] = c; }
        __syncthreads();
        if (tid == 0){
            ws[MEANS+0] = (sa[0]+sa[1]+sa[2]+sa[3]) * (1.f/NN);
            ws[MEANS+1] = (sc[0]+sc[1]+sc[2]+sc[3]) * (1.f/NN);
        }
        return;
    }
    int b = blockIdx.x - 1;
    int job = b >> 10;
    int rowbase = (b & 1023) * 4;
    const float* x; float* o;
    switch (job){
      case 0: x = ws+RS0; o = ws+VI0;  break;
      case 1: x = ws+RI0; o = ws+VA0A; break;
      case 2: x = ws+RS1; o = ws+VA0B; break;
      case 3: x = ws+RS0; o = ws+VB1;  break;
      case 4: x = ws+RS1; o = ws+VI1;  break;
      case 5: x = ws+RI1; o = ws+VA1A; break;
      case 6: x = ws+RS2; o = ws+VA1B; break;
      default:x = ws+RS1; o = ws+VB2;  break;
    }
    __shared__ float xs[NN];
    mv_rows_h(wh + (size_t)job * MAT_ELEMS, x, o, rowbase, xs);
}

__global__ void k_update(float* __restrict__ ws){
    const float DT=0.1f, GA=0.8f, GB=1.0f, GD=1.0f, GLK=0.1f, GSOM=0.8f;
    int i = blockIdx.x*blockDim.x + threadIdx.x;
    if (i >= NN) return;
    float s0=ws[SS0+i], s1=ws[SS1+i], s2=ws[SS2+i], i0=ws[II0+i], i1=ws[II1+i];
    float vb0=ws[VB0+i], vb1=ws[VB1+i], vb2=ws[VB2+i];
    float va0=ws[VA0A+i]+ws[VA0B+i];
    float va1=ws[VA1A+i]+ws[VA1B+i];
    float vi0=ws[VI0+i], vi1=ws[VI1+i];
    float m0=ws[MEANS+0], m1=ws[MEANS+1];
    float ds0 = -GLK*s0 + GB*(vb0-s0) + GA*(va0-s0);
    float ds1 = -GLK*s1 + GB*(vb1-s1) + GA*(va1-s1);
    float ds2 = -GLK*s2 + GB*(vb2-s2);
    float di0 = -GLK*i0 + GD*(vi0-i0) + GSOM*(m0-i0);
    float di1 = -GLK*i1 + GD*(vi1-i1) + GSOM*(m1-i1);
    float ns0 = s0 + DT*ds0;
    float ns1 = s1 + DT*ds1;
    float ns2 = DT*ds2;          // faithful to reference: assignment, not +=
    float ni0 = i0 + DT*di0;
    float ni1 = i1 + DT*di1;
    ws[SS0+i]=ns0; ws[SS1+i]=ns1; ws[SS2+i]=ns2; ws[II0+i]=ni0; ws[II1+i]=ni1;
    ws[RS0+i]=softplusf(ns0); ws[RS1+i]=softplusf(ns1); ws[RS2+i]=softplusf(ns2);
    ws[RI0+i]=softplusf(ni0); ws[RI1+i]=softplusf(ni1);
}

__global__ void k_out(const float* __restrict__ ws, float* __restrict__ out){
    int i = blockIdx.x*blockDim.x + threadIdx.x;
    if (i >= 5*NN) return;
    int which = i >> 12;
    int off = i & (NN-1);
    const int src[5] = {SS0, SS1, SS2, II0, II1};
    out[i] = ws[src[which] + off];
}

extern "C" void kernel_launch(void* const* d_in, const int* in_sizes, int n_in,
                              void* d_out, int out_size, void* d_ws, size_t ws_size,
                              hipStream_t stream) {
    const float* data = (const float*)d_in[0];
    const float* s0   = (const float*)d_in[1];
    const float* s1   = (const float*)d_in[2];
    const float* s2   = (const float*)d_in[3];
    const float* i0   = (const float*)d_in[4];
    const float* i1   = (const float*)d_in[5];
    const float* wpf0 = (const float*)d_in[6];
    const float* wpf1 = (const float*)d_in[7];
    const float* wpf2 = (const float*)d_in[8];
    const float* wpb0 = (const float*)d_in[9];
    const float* wpb1 = (const float*)d_in[10];
    const float* wip0 = (const float*)d_in[11];
    const float* wip1 = (const float*)d_in[12];
    const float* wpi0 = (const float*)d_in[13];
    const float* wpi1 = (const float*)d_in[14];
    float* ws  = (float*)d_ws;
    float* out = (float*)d_out;

    k_init<<<(NN+255)/256, 256, 0, stream>>>(data, s0, s1, s2, i0, i1, ws);
    k_vb0<<<NN/4, 256, 0, stream>>>(wpf0, ws);

    if (ws_size >= WS_NEEDED_FP16){
        _Float16* wh = (_Float16*)((char*)d_ws + WS_F32_BYTES);
        const float* srcs[8] = {wip0, wpi0, wpb0, wpf1, wip1, wpi1, wpb1, wpf2};
        const int cvt_blocks = (int)(MAT_ELEMS/8/256);   // 8192
        for (int j = 0; j < 8; ++j)
            k_cvt<<<cvt_blocks, 256, 0, stream>>>(srcs[j], wh + (size_t)j*MAT_ELEMS);
        for (int t = 0; t < TSTEPS; ++t){
            k_mv_h<<<8*NN/4 + 1, 256, 0, stream>>>(ws, wh);
            k_update<<<(NN+255)/256, 256, 0, stream>>>(ws);
        }
    } else {
        for (int t = 0; t < TSTEPS; ++t){
            k_mv<<<8*NN/4 + 1, 256, 0, stream>>>(wip0, wpi0, wpb0, wpf1,
                                                 wip1, wpi1, wpb1, wpf2, ws);
            k_update<<<(NN+255)/256, 256, 0, stream>>>(ws);
        }
    }
    k_out<<<(5*NN+255)/256, 256, 0, stream>>>(ws, out);
}